// Round 1
// baseline (4131.990 us; speedup 1.0000x reference)
//
#include <hip/hip_runtime.h>
#include <hip/hip_bf16.h>

typedef __hip_bfloat16 bf16;

#define BATCH 4
#define HH 512
#define WW 512

__device__ __forceinline__ float loadVal(const float* p) { return *p; }
__device__ __forceinline__ float loadVal(const bf16* p) { return __bfloat162float(*p); }
__device__ __forceinline__ void storeVal(float* p, float v) { *p = v; }
__device__ __forceinline__ void storeVal(bf16* p, float v) { *p = __float2bfloat16(v); }

// ---------------------------------------------------------------------------
// 3x3 conv, pad 1, fused bias + activation (ACT 0=relu, 1=tanh).
// Block: (8,8,NG). 16x16 spatial tile; each thread: 2x2 pixels x (COUT/NG) couts.
// One wave per z-slice => weight/bias indices wave-uniform => s_load path.
// ---------------------------------------------------------------------------
template <typename InT, typename OutT, int CIN, int COUT, int NG, int CK, int ACT>
__global__ __launch_bounds__(256) void conv3x3(const InT* __restrict__ in,
                                               const float* __restrict__ w,
                                               const float* __restrict__ bias,
                                               OutT* __restrict__ out,
                                               int H, int W) {
  constexpr int CO_PER = COUT / NG;
  constexpr int NT = 64 * NG;
  __shared__ float tile[CK][18][18];

  const int tx = threadIdx.x;            // 0..7
  const int ty = threadIdx.y;            // 0..7
  const int tzu = __builtin_amdgcn_readfirstlane((int)threadIdx.z);  // wave-uniform
  const int b = blockIdx.z;
  const int x0 = blockIdx.x * 16;
  const int y0 = blockIdx.y * 16;
  const int tid = tx + ty * 8 + threadIdx.z * 64;

  float acc[2][2][CO_PER];
#pragma unroll
  for (int co = 0; co < CO_PER; ++co) {
    float bv = bias[tzu * CO_PER + co];
    acc[0][0][co] = bv; acc[0][1][co] = bv; acc[1][0][co] = bv; acc[1][1][co] = bv;
  }

  for (int c0 = 0; c0 < CIN; c0 += CK) {
    // cooperative load CK x 18 x 18 input tile (zero-padded)
    for (int e = tid; e < CK * 324; e += NT) {
      int c = e / 324;
      int rem = e - c * 324;
      int r = rem / 18;
      int s = rem - r * 18;
      int gy = y0 - 1 + r;
      int gx = x0 - 1 + s;
      float v = 0.0f;
      if (gy >= 0 && gy < H && gx >= 0 && gx < W)
        v = loadVal(in + (((long)b * CIN + c0 + c) * H + gy) * (long)W + gx);
      tile[c][r][s] = v;
    }
    __syncthreads();

#pragma unroll
    for (int c = 0; c < CK; ++c) {
      float win[4][4];
#pragma unroll
      for (int r = 0; r < 4; ++r)
#pragma unroll
        for (int s = 0; s < 4; ++s) win[r][s] = tile[c][ty * 2 + r][tx * 2 + s];

#pragma unroll
      for (int co = 0; co < CO_PER; ++co) {
        const float* wp = w + (((tzu * CO_PER + co) * CIN) + c0 + c) * 9;
        float w0 = wp[0], w1 = wp[1], w2 = wp[2];
        float w3 = wp[3], w4 = wp[4], w5 = wp[5];
        float w6 = wp[6], w7 = wp[7], w8 = wp[8];
#pragma unroll
        for (int p = 0; p < 2; ++p)
#pragma unroll
          for (int q = 0; q < 2; ++q) {
            acc[p][q][co] += win[p + 0][q + 0] * w0 + win[p + 0][q + 1] * w1 +
                             win[p + 0][q + 2] * w2 + win[p + 1][q + 0] * w3 +
                             win[p + 1][q + 1] * w4 + win[p + 1][q + 2] * w5 +
                             win[p + 2][q + 0] * w6 + win[p + 2][q + 1] * w7 +
                             win[p + 2][q + 2] * w8;
          }
      }
    }
    __syncthreads();
  }

#pragma unroll
  for (int co = 0; co < CO_PER; ++co) {
    int coo = tzu * CO_PER + co;
#pragma unroll
    for (int p = 0; p < 2; ++p) {
      int y = y0 + ty * 2 + p;
#pragma unroll
      for (int q = 0; q < 2; ++q) {
        int x = x0 + tx * 2 + q;
        float v = acc[p][q][co];
        if (ACT == 0)
          v = fmaxf(v, 0.0f);
        else
          v = tanhf(v);
        storeVal(out + (((long)b * COUT + coo) * H + y) * (long)W + x, v);
      }
    }
  }
}

// ---------------------------------------------------------------------------
// MaxPool2d(2)
// ---------------------------------------------------------------------------
__global__ __launch_bounds__(256) void maxpool2(const bf16* __restrict__ in,
                                                bf16* __restrict__ out, int C,
                                                int H, int W, int total) {
  int i = blockIdx.x * 256 + threadIdx.x;
  if (i >= total) return;
  int Ho = H >> 1, Wo = W >> 1;
  int x = i % Wo;
  int t = i / Wo;
  int y = t % Ho;
  t /= Ho;  // t = b*C + c
  const bf16* p = in + ((long)t * H + 2 * y) * (long)W + 2 * x;
  float a = loadVal(p), b2 = loadVal(p + 1);
  float c2 = loadVal(p + W), d = loadVal(p + W + 1);
  out[i] = __float2bfloat16(fmaxf(fmaxf(a, b2), fmaxf(c2, d)));
}

// ---------------------------------------------------------------------------
// Bilinear upsample x2 (half-pixel, edge clamp) == jax.image.resize bilinear
// ---------------------------------------------------------------------------
__global__ __launch_bounds__(256) void upsample2(const bf16* __restrict__ in,
                                                 bf16* __restrict__ out, int C,
                                                 int H, int W, int total) {
  int i = blockIdx.x * 256 + threadIdx.x;
  if (i >= total) return;
  int Ho = 2 * H, Wo = 2 * W;
  int x = i % Wo;
  int t = i / Wo;
  int y = t % Ho;
  t /= Ho;  // t = b*C + c
  float sy = y * 0.5f - 0.25f;
  float sx = x * 0.5f - 0.25f;
  int y0 = (int)floorf(sy);
  int x0 = (int)floorf(sx);
  float wy = sy - (float)y0;
  float wx = sx - (float)x0;
  int y0c = max(y0, 0), y1c = min(y0 + 1, H - 1);
  int x0c = max(x0, 0), x1c = min(x0 + 1, W - 1);
  const bf16* p = in + (long)t * H * W;
  float v00 = loadVal(p + y0c * W + x0c), v01 = loadVal(p + y0c * W + x1c);
  float v10 = loadVal(p + y1c * W + x0c), v11 = loadVal(p + y1c * W + x1c);
  float v = (1.0f - wy) * ((1.0f - wx) * v00 + wx * v01) +
            wy * ((1.0f - wx) * v10 + wx * v11);
  out[i] = __float2bfloat16(v);
}

// ---------------------------------------------------------------------------
// deformed = base_grid + flow.transpose(0,2,3,1) * temp   -> [B,H,W,2]
// ---------------------------------------------------------------------------
__global__ __launch_bounds__(256) void deformed_k(const float* __restrict__ flow,
                                                  const float* __restrict__ temp,
                                                  float* __restrict__ def) {
  int i = blockIdx.x * 256 + threadIdx.x;  // over B*H*W
  if (i >= BATCH * HH * WW) return;
  int x = i % WW;
  int t = i / WW;
  int y = t % HH;
  int b = t / HH;
  float T = temp[0];
  float gx = -1.0f + x * (2.0f / 511.0f);
  float gy = -1.0f + y * (2.0f / 511.0f);
  float fx = flow[((long)(b * 2 + 0) * HH + y) * WW + x];
  float fy = flow[((long)(b * 2 + 1) * HH + y) * WW + x];
  def[(long)i * 2 + 0] = gx + fx * T;
  def[(long)i * 2 + 1] = gy + fy * T;
}

// ---------------------------------------------------------------------------
// patches: grid_sample bilinear, zeros padding, align_corners=False
// out [B,256,3,64,64]
// ---------------------------------------------------------------------------
__global__ __launch_bounds__(256) void patches_k(const float* __restrict__ x,
                                                 const float* __restrict__ def,
                                                 float* __restrict__ out) {
  int i = blockIdx.x * 256 + threadIdx.x;  // over B*256*64*64
  int pj = i & 63;
  int t = i >> 6;
  int pi = t & 63;
  t >>= 6;
  int n = t & 255;
  int b = t >> 8;
  if (b >= BATCH) return;
  int hi = n >> 4, wi = n & 15;
  const float* dptr = def + (((long)b * HH + hi * 32) * WW + wi * 32) * 2;
  float cx = dptr[0], cy = dptr[1];
  float pgx = cx + (-1.0f + pj * (2.0f / 63.0f)) * 0.125f;
  float pgy = cy + (-1.0f + pi * (2.0f / 63.0f)) * 0.125f;
  float ix = ((pgx + 1.0f) * 512.0f - 1.0f) * 0.5f;
  float iy = ((pgy + 1.0f) * 512.0f - 1.0f) * 0.5f;
  float fx0 = floorf(ix), fy0 = floorf(iy);
  float wx1 = ix - fx0, wy1 = iy - fy0;
  int x0 = (int)fx0, y0 = (int)fy0;
  int x1 = x0 + 1, y1 = y0 + 1;
  bool vx0 = (x0 >= 0) && (x0 <= 511), vx1 = (x1 >= 0) && (x1 <= 511);
  bool vy0 = (y0 >= 0) && (y0 <= 511), vy1 = (y1 >= 0) && (y1 <= 511);
  int cx0 = min(max(x0, 0), 511), cx1 = min(max(x1, 0), 511);
  int cy0 = min(max(y0, 0), 511), cy1 = min(max(y1, 0), 511);
  float w00 = (1.0f - wx1) * (1.0f - wy1) * ((vx0 && vy0) ? 1.0f : 0.0f);
  float w01 = wx1 * (1.0f - wy1) * ((vx1 && vy0) ? 1.0f : 0.0f);
  float w10 = (1.0f - wx1) * wy1 * ((vx0 && vy1) ? 1.0f : 0.0f);
  float w11 = wx1 * wy1 * ((vx1 && vy1) ? 1.0f : 0.0f);
#pragma unroll
  for (int c = 0; c < 3; ++c) {
    const float* img = x + ((long)b * 3 + c) * (HH * WW);
    float v = img[cy0 * WW + cx0] * w00 + img[cy0 * WW + cx1] * w01 +
              img[cy1 * WW + cx0] * w10 + img[cy1 * WW + cx1] * w11;
    out[(((long)b * 256 + n) * 3 + c) * 4096 + pi * 64 + pj] = v;
  }
}

// ---------------------------------------------------------------------------

extern "C" void kernel_launch(void* const* d_in, const int* in_sizes, int n_in,
                              void* d_out, int out_size, void* d_ws,
                              size_t ws_size, hipStream_t stream) {
  const float* x = (const float*)d_in[0];
  const float* w[8];
  const float* bs[8];
  for (int i = 0; i < 8; ++i) {
    w[i] = (const float*)d_in[1 + 2 * i];
    bs[i] = (const float*)d_in[2 + 2 * i];
  }
  const float* temp = (const float*)d_in[17];

  float* out = (float*)d_out;
  float* flow = out + 12582912;   // [B,2,512,512]
  float* def = out + 14680064;    // [B,512,512,2]

  // two bf16 ping-pong activation buffers, each 4*32*512*512 elems = 64 MiB
  const size_t bufElems = (size_t)BATCH * 32 * 512 * 512;
  bf16* A = (bf16*)d_ws;
  bf16* Bf = A + bufElems;

  dim3 blk4(8, 8, 4);
  dim3 g512(32, 32, BATCH);
  dim3 g256(16, 16, BATCH);

  // conv0: x(f32,3ch) -> A  [32x512x512]
  conv3x3<float, bf16, 3, 32, 4, 3, 0><<<g512, blk4, 0, stream>>>(x, w[0], bs[0], A, 512, 512);
  // conv1: A -> Bf [32x512x512]
  conv3x3<bf16, bf16, 32, 32, 4, 4, 0><<<g512, blk4, 0, stream>>>(A, w[1], bs[1], Bf, 512, 512);
  // pool: Bf -> A [32x256x256]
  {
    int total = BATCH * 32 * 256 * 256;
    maxpool2<<<(total + 255) / 256, 256, 0, stream>>>(Bf, A, 32, 512, 512, total);
  }
  // conv2: A -> Bf [64x256x256]
  conv3x3<bf16, bf16, 32, 64, 4, 4, 0><<<g256, blk4, 0, stream>>>(A, w[2], bs[2], Bf, 256, 256);
  // conv3: Bf -> A [64x256x256]
  conv3x3<bf16, bf16, 64, 64, 4, 4, 0><<<g256, blk4, 0, stream>>>(Bf, w[3], bs[3], A, 256, 256);
  // pool: A -> Bf [64x128x128]
  {
    int total = BATCH * 64 * 128 * 128;
    maxpool2<<<(total + 255) / 256, 256, 0, stream>>>(A, Bf, 64, 256, 256, total);
  }
  // up: Bf -> A [64x256x256]
  {
    int total = BATCH * 64 * 256 * 256;
    upsample2<<<(total + 255) / 256, 256, 0, stream>>>(Bf, A, 64, 128, 128, total);
  }
  // conv4: A -> Bf [64x256x256]
  conv3x3<bf16, bf16, 64, 64, 4, 4, 0><<<g256, blk4, 0, stream>>>(A, w[4], bs[4], Bf, 256, 256);
  // conv5: Bf -> A [32x256x256]
  conv3x3<bf16, bf16, 64, 32, 4, 4, 0><<<g256, blk4, 0, stream>>>(Bf, w[5], bs[5], A, 256, 256);
  // up: A -> Bf [32x512x512]
  {
    int total = BATCH * 32 * 512 * 512;
    upsample2<<<(total + 255) / 256, 256, 0, stream>>>(A, Bf, 32, 256, 256, total);
  }
  // conv6: Bf -> A [32x512x512]
  conv3x3<bf16, bf16, 32, 32, 4, 4, 0><<<g512, blk4, 0, stream>>>(Bf, w[6], bs[6], A, 512, 512);
  // conv7 + tanh: A -> flow (f32) [2x512x512]
  conv3x3<bf16, float, 32, 2, 2, 4, 1><<<g512, dim3(8, 8, 2), 0, stream>>>(A, w[7], bs[7], flow, 512, 512);
  // deformed
  {
    int total = BATCH * HH * WW;
    deformed_k<<<(total + 255) / 256, 256, 0, stream>>>(flow, temp, def);
  }
  // patches
  {
    int total = BATCH * 256 * 64 * 64;
    patches_k<<<(total + 255) / 256, 256, 0, stream>>>(x, def, out);
  }
}

// Round 2
// 432.595 us; speedup vs baseline: 9.5516x; 9.5516x over previous
//
#include <hip/hip_runtime.h>
#include <hip/hip_bf16.h>

typedef __hip_bfloat16 bf16;
typedef unsigned short ushort_t;
typedef __attribute__((ext_vector_type(8))) short short8;
typedef __attribute__((ext_vector_type(4))) float float4v;

#define BATCH 4
#define HH 512
#define WW 512

__device__ __forceinline__ ushort_t f2bfu(float f) {
  __hip_bfloat16 h = __float2bfloat16(f);
  union { __hip_bfloat16 h; ushort_t u; } c;
  c.h = h;
  return c.u;
}
__device__ __forceinline__ float bfu2f(ushort_t u) {
  return __uint_as_float(((unsigned)u) << 16);
}

// ---------------------------------------------------------------------------
// Weight prep: w[l] OIHW f32  ->  wT[l] = [tap(9)][COUT_PAD][CIN_PAD] bf16
// (zero-padded). One launch, grid.y = layer.
// ---------------------------------------------------------------------------
struct WP { const float* w[8]; };

__global__ __launch_bounds__(256) void prep_w(WP wp, bf16* __restrict__ dst) {
  const int O[8]   = {32, 32, 64, 64, 64, 32, 32, 2};
  const int I[8]   = {3, 32, 32, 64, 64, 64, 32, 32};
  const int OP[8]  = {32, 32, 64, 64, 64, 32, 32, 16};
  const int IP[8]  = {32, 32, 32, 64, 64, 64, 32, 32};
  const int OFF[8] = {0, 9216, 18432, 36864, 73728, 110592, 129024, 138240};
  int l = blockIdx.y;
  int e = blockIdx.x * 256 + threadIdx.x;
  int n = 9 * OP[l] * IP[l];
  if (e >= n) return;
  int tap = e / (OP[l] * IP[l]);
  int rem = e - tap * OP[l] * IP[l];
  int o = rem / IP[l];
  int i = rem - o * IP[l];
  float v = 0.0f;
  if (o < O[l] && i < I[l]) v = wp.w[l][((o * I[l]) + i) * 9 + tap];
  dst[OFF[l] + e] = __float2bfloat16(v);
}

// ---------------------------------------------------------------------------
// Implicit-GEMM 3x3 conv (pad 1) via mfma_f32_16x16x32_bf16.
// Activations NHWC bf16. Block: 256 thr (4 waves), 16x16 pixel tile.
// Wave w: pixels n in [64w,64w+64) (rows py=4w..4w+3), all COUT.
// A (weights): lane holds A[m=lane&15][k=quad*8+j]   (w_lds[tap][o][c])
// B (input):   lane holds B[k=quad*8+j][n=lane&15]   (in_lds[pix][c])
// D: cout = mt*16 + quad*4 + reg, pixel col = lane&15   [m89/m91 layout]
// ---------------------------------------------------------------------------
template <int CIN, int COUT, int CINR, int COUTR, int ACT, bool IN_NCHW_F32,
          bool OUT_NCHW_F32>
__global__ __launch_bounds__(256) void conv_mfma(const void* __restrict__ in_,
                                                 const bf16* __restrict__ wt,
                                                 const float* __restrict__ bias,
                                                 void* __restrict__ out_,
                                                 int H, int W) {
  constexpr int MT = COUT / 16;
  constexpr int CK = 32;
  __shared__ alignas(16) bf16 in_lds[324 * CK];        // 18x18 halo x 32ch
  __shared__ alignas(16) bf16 w_lds[9 * COUT * CK];

  const int tid = threadIdx.x;
  const int lane = tid & 63;
  const int wid = tid >> 6;
  const int lm = lane & 15;
  const int quad = lane >> 4;
  const int x0 = blockIdx.x * 16;
  const int y0 = blockIdx.y * 16;
  const int b = blockIdx.z;

  float4v acc[MT][4];
#pragma unroll
  for (int mt = 0; mt < MT; ++mt) {
    float4v bv;
    if constexpr (COUTR == COUT) {
      bv = *(const float4v*)(bias + mt * 16 + quad * 4);
    } else {
#pragma unroll
      for (int r = 0; r < 4; ++r) {
        int co = mt * 16 + quad * 4 + r;
        bv[r] = (co < COUTR) ? bias[co] : 0.0f;
      }
    }
#pragma unroll
    for (int nt = 0; nt < 4; ++nt) acc[mt][nt] = bv;
  }

  for (int c0 = 0; c0 < CIN; c0 += CK) {
    // ---- stage input halo tile into LDS (NHWC, channels contiguous) ----
    if constexpr (IN_NCHW_F32) {
      // conv0: x is NCHW f32 with CINR(=3) real channels; pad to CK zeros.
      const float* in = (const float*)in_;
      const uint4 z = {0, 0, 0, 0};
      for (int pix = tid; pix < 324; pix += 256) {
        int hy = pix / 18, hx = pix - hy * 18;
        int gy = y0 - 1 + hy, gx = x0 - 1 + hx;
        union { uint4 v; ushort_t u[8]; } pk;
        pk.v = z;
        if (gy >= 0 && gy < H && gx >= 0 && gx < W) {
          long base = (((long)b * CINR) * H + gy) * (long)W + gx;
#pragma unroll
          for (int c = 0; c < CINR; ++c)
            pk.u[c] = f2bfu(in[base + (long)c * H * W]);
        }
        uint4* dst = (uint4*)&in_lds[pix * CK];
        dst[0] = pk.v;
        dst[1] = z;
        dst[2] = z;
        dst[3] = z;
      }
    } else {
      const bf16* in = (const bf16*)in_;
      for (int u = tid; u < 324 * 4; u += 256) {
        int pix = u >> 2;
        int seg = u & 3;
        int hy = pix / 18, hx = pix - hy * 18;
        int gy = y0 - 1 + hy, gx = x0 - 1 + hx;
        uint4 v = {0, 0, 0, 0};
        if (gy >= 0 && gy < H && gx >= 0 && gx < W)
          v = *(const uint4*)(in + (((long)b * H + gy) * W + gx) * CIN + c0 +
                              seg * 8);
        *(uint4*)&in_lds[pix * CK + seg * 8] = v;
      }
    }
    // ---- stage weight chunk [9][COUT][CK] ----
    {
      constexpr int WUNITS = 9 * COUT * CK / 8;
      for (int u = tid; u < WUNITS; u += 256) {
        int to = u >> 2;
        int seg = u & 3;
        uint4 v = *(const uint4*)(wt + (long)to * CIN + c0 + seg * 8);
        *(uint4*)&w_lds[to * CK + seg * 8] = v;
      }
    }
    __syncthreads();

    // ---- 9 taps x K=32 MFMA ----
#pragma unroll
    for (int tap = 0; tap < 9; ++tap) {
      const int r = tap / 3, s = tap - r * 3;
      short8 afrag[MT], bfrag[4];
#pragma unroll
      for (int mt = 0; mt < MT; ++mt)
        afrag[mt] =
            *(const short8*)&w_lds[(tap * COUT + mt * 16 + lm) * CK + quad * 8];
#pragma unroll
      for (int nt = 0; nt < 4; ++nt) {
        int py = 4 * wid + nt;
        bfrag[nt] =
            *(const short8*)&in_lds[((py + r) * 18 + lm + s) * CK + quad * 8];
      }
#pragma unroll
      for (int mt = 0; mt < MT; ++mt)
#pragma unroll
        for (int nt = 0; nt < 4; ++nt)
          acc[mt][nt] = __builtin_amdgcn_mfma_f32_16x16x32_bf16(
              afrag[mt], bfrag[nt], acc[mt][nt], 0, 0, 0);
    }
    __syncthreads();
  }

  // ---- epilogue ----
#pragma unroll
  for (int mt = 0; mt < MT; ++mt) {
#pragma unroll
    for (int nt = 0; nt < 4; ++nt) {
      int gy = y0 + 4 * wid + nt;
      int gx = x0 + lm;
      float4v v = acc[mt][nt];
      if constexpr (!OUT_NCHW_F32) {
        bf16* out = (bf16*)out_;
        union { uint2 v; ushort_t u[4]; } pk;
#pragma unroll
        for (int r = 0; r < 4; ++r) {
          float f = v[r];
          if (ACT == 0) f = fmaxf(f, 0.0f);
          pk.u[r] = f2bfu(f);
        }
        *(uint2*)&out[(((long)b * H + gy) * W + gx) * COUT + mt * 16 +
                      quad * 4] = pk.v;
      } else {
        float* out = (float*)out_;
#pragma unroll
        for (int r = 0; r < 4; ++r) {
          int co = mt * 16 + quad * 4 + r;
          if (co < COUTR) {
            float f = v[r];
            if (ACT == 0)
              f = fmaxf(f, 0.0f);
            else
              f = tanhf(f);
            out[(((long)b * COUTR + co) * H + gy) * (long)W + gx] = f;
          }
        }
      }
    }
  }
}

// ---------------------------------------------------------------------------
// MaxPool2d(2) NHWC, 8 channels per thread (uint4). Exact (picks argmax bits).
// ---------------------------------------------------------------------------
__global__ __launch_bounds__(256) void maxpool2_nhwc(const bf16* __restrict__ in,
                                                     bf16* __restrict__ out,
                                                     int C, int H, int W,
                                                     int total8) {
  int i = blockIdx.x * 256 + threadIdx.x;
  if (i >= total8) return;
  int C8 = C >> 3;
  int c8 = i % C8;
  int t = i / C8;
  int Wo = W >> 1, Ho = H >> 1;
  int x = t % Wo;
  t /= Wo;
  int y = t % Ho;
  int bb = t / Ho;
  const bf16* p = in + ((((long)bb * H + 2 * y) * W + 2 * x) * C) + c8 * 8;
  union U { uint4 v; ushort_t u[8]; } a, b2, c2, d, o;
  a.v = *(const uint4*)p;
  b2.v = *(const uint4*)(p + C);
  c2.v = *(const uint4*)(p + (long)W * C);
  d.v = *(const uint4*)(p + (long)W * C + C);
#pragma unroll
  for (int j = 0; j < 8; ++j) {
    float fm = bfu2f(a.u[j]);
    ushort_t m = a.u[j];
    float f = bfu2f(b2.u[j]);
    if (f > fm) { fm = f; m = b2.u[j]; }
    f = bfu2f(c2.u[j]);
    if (f > fm) { fm = f; m = c2.u[j]; }
    f = bfu2f(d.u[j]);
    if (f > fm) { fm = f; m = d.u[j]; }
    o.u[j] = m;
  }
  *(uint4*)(out + ((((long)bb * Ho + y) * Wo + x) * C) + c8 * 8) = o.v;
}

// ---------------------------------------------------------------------------
// Bilinear upsample x2 (half-pixel, edge clamp) NHWC, 8 ch per thread.
// ---------------------------------------------------------------------------
__global__ __launch_bounds__(256) void upsample2_nhwc(const bf16* __restrict__ in,
                                                      bf16* __restrict__ out,
                                                      int C, int H, int W,
                                                      int total8) {
  int i = blockIdx.x * 256 + threadIdx.x;
  if (i >= total8) return;
  int C8 = C >> 3;
  int c8 = i % C8;
  int t = i / C8;
  int Wo = 2 * W, Ho = 2 * H;
  int x = t % Wo;
  t /= Wo;
  int y = t % Ho;
  int bb = t / Ho;
  float sy = y * 0.5f - 0.25f;
  float sx = x * 0.5f - 0.25f;
  int y0 = (int)floorf(sy);
  int x0 = (int)floorf(sx);
  float wy = sy - (float)y0;
  float wx = sx - (float)x0;
  int y0c = max(y0, 0), y1c = min(y0 + 1, H - 1);
  int x0c = max(x0, 0), x1c = min(x0 + 1, W - 1);
  const bf16* p = in + ((long)bb * H * W) * C + c8 * 8;
  union U { uint4 v; ushort_t u[8]; } v00, v01, v10, v11, o;
  v00.v = *(const uint4*)(p + ((long)y0c * W + x0c) * C);
  v01.v = *(const uint4*)(p + ((long)y0c * W + x1c) * C);
  v10.v = *(const uint4*)(p + ((long)y1c * W + x0c) * C);
  v11.v = *(const uint4*)(p + ((long)y1c * W + x1c) * C);
#pragma unroll
  for (int j = 0; j < 8; ++j) {
    float f = (1.0f - wy) * ((1.0f - wx) * bfu2f(v00.u[j]) + wx * bfu2f(v01.u[j])) +
              wy * ((1.0f - wx) * bfu2f(v10.u[j]) + wx * bfu2f(v11.u[j]));
    o.u[j] = f2bfu(f);
  }
  *(uint4*)(out + ((((long)bb * Ho + y) * Wo + x) * C) + c8 * 8) = o.v;
}

// ---------------------------------------------------------------------------
// deformed = base_grid + flow.transpose(0,2,3,1) * temp   -> [B,H,W,2]
// ---------------------------------------------------------------------------
__global__ __launch_bounds__(256) void deformed_k(const float* __restrict__ flow,
                                                  const float* __restrict__ temp,
                                                  float* __restrict__ def) {
  int i = blockIdx.x * 256 + threadIdx.x;
  if (i >= BATCH * HH * WW) return;
  int x = i % WW;
  int t = i / WW;
  int y = t % HH;
  int b = t / HH;
  float T = temp[0];
  float gx = -1.0f + x * (2.0f / 511.0f);
  float gy = -1.0f + y * (2.0f / 511.0f);
  float fx = flow[((long)(b * 2 + 0) * HH + y) * WW + x];
  float fy = flow[((long)(b * 2 + 1) * HH + y) * WW + x];
  def[(long)i * 2 + 0] = gx + fx * T;
  def[(long)i * 2 + 1] = gy + fy * T;
}

// ---------------------------------------------------------------------------
// patches: grid_sample bilinear, zeros padding -> out [B,256,3,64,64]
// ---------------------------------------------------------------------------
__global__ __launch_bounds__(256) void patches_k(const float* __restrict__ x,
                                                 const float* __restrict__ def,
                                                 float* __restrict__ out) {
  int i = blockIdx.x * 256 + threadIdx.x;
  int pj = i & 63;
  int t = i >> 6;
  int pi = t & 63;
  t >>= 6;
  int n = t & 255;
  int b = t >> 8;
  if (b >= BATCH) return;
  int hi = n >> 4, wi = n & 15;
  const float* dptr = def + (((long)b * HH + hi * 32) * WW + wi * 32) * 2;
  float cx = dptr[0], cy = dptr[1];
  float pgx = cx + (-1.0f + pj * (2.0f / 63.0f)) * 0.125f;
  float pgy = cy + (-1.0f + pi * (2.0f / 63.0f)) * 0.125f;
  float ix = ((pgx + 1.0f) * 512.0f - 1.0f) * 0.5f;
  float iy = ((pgy + 1.0f) * 512.0f - 1.0f) * 0.5f;
  float fx0 = floorf(ix), fy0 = floorf(iy);
  float wx1 = ix - fx0, wy1 = iy - fy0;
  int x0 = (int)fx0, y0 = (int)fy0;
  int x1 = x0 + 1, y1 = y0 + 1;
  bool vx0 = (x0 >= 0) && (x0 <= 511), vx1 = (x1 >= 0) && (x1 <= 511);
  bool vy0 = (y0 >= 0) && (y0 <= 511), vy1 = (y1 >= 0) && (y1 <= 511);
  int cx0 = min(max(x0, 0), 511), cx1 = min(max(x1, 0), 511);
  int cy0 = min(max(y0, 0), 511), cy1 = min(max(y1, 0), 511);
  float w00 = (1.0f - wx1) * (1.0f - wy1) * ((vx0 && vy0) ? 1.0f : 0.0f);
  float w01 = wx1 * (1.0f - wy1) * ((vx1 && vy0) ? 1.0f : 0.0f);
  float w10 = (1.0f - wx1) * wy1 * ((vx0 && vy1) ? 1.0f : 0.0f);
  float w11 = wx1 * wy1 * ((vx1 && vy1) ? 1.0f : 0.0f);
#pragma unroll
  for (int c = 0; c < 3; ++c) {
    const float* img = x + ((long)b * 3 + c) * (HH * WW);
    float v = img[cy0 * WW + cx0] * w00 + img[cy0 * WW + cx1] * w01 +
              img[cy1 * WW + cx0] * w10 + img[cy1 * WW + cx1] * w11;
    out[(((long)b * 256 + n) * 3 + c) * 4096 + pi * 64 + pj] = v;
  }
}

// ---------------------------------------------------------------------------

extern "C" void kernel_launch(void* const* d_in, const int* in_sizes, int n_in,
                              void* d_out, int out_size, void* d_ws,
                              size_t ws_size, hipStream_t stream) {
  const float* x = (const float*)d_in[0];
  WP wp;
  const float* bs[8];
  for (int i = 0; i < 8; ++i) {
    wp.w[i] = (const float*)d_in[1 + 2 * i];
    bs[i] = (const float*)d_in[2 + 2 * i];
  }
  const float* temp = (const float*)d_in[17];

  float* out = (float*)d_out;
  float* flow = out + 12582912;  // [B,2,512,512] f32
  float* def = out + 14680064;   // [B,512,512,2] f32

  // Transposed bf16 weights live at the head of the patches region of d_out
  // (286 KB of 50 MB); patches_k overwrites it LAST. ws stays at 128 MiB.
  bf16* wT = (bf16*)d_out;
  const int WOFF[8] = {0, 9216, 18432, 36864, 73728, 110592, 129024, 138240};

  // two bf16 NHWC ping-pong activation buffers, 64 MiB each
  const size_t bufElems = (size_t)BATCH * 512 * 512 * 32;
  bf16* A = (bf16*)d_ws;
  bf16* Bf = A + bufElems;

  prep_w<<<dim3(144, 8), 256, 0, stream>>>(wp, wT);

  dim3 g512(32, 32, BATCH);
  dim3 g256(16, 16, BATCH);

  // conv0: x (NCHW f32, 3ch) -> A NHWC [512,512,32]
  conv_mfma<32, 32, 3, 32, 0, true, false>
      <<<g512, 256, 0, stream>>>(x, wT + WOFF[0], bs[0], A, 512, 512);
  // conv1: A -> Bf NHWC [512,512,32]
  conv_mfma<32, 32, 32, 32, 0, false, false>
      <<<g512, 256, 0, stream>>>(A, wT + WOFF[1], bs[1], Bf, 512, 512);
  // pool1: Bf -> A [256,256,32]
  {
    int total8 = BATCH * 256 * 256 * 32 / 8;
    maxpool2_nhwc<<<(total8 + 255) / 256, 256, 0, stream>>>(Bf, A, 32, 512, 512, total8);
  }
  // conv2: A -> Bf [256,256,64]
  conv_mfma<32, 64, 32, 64, 0, false, false>
      <<<g256, 256, 0, stream>>>(A, wT + WOFF[2], bs[2], Bf, 256, 256);
  // conv3: Bf -> A [256,256,64]
  conv_mfma<64, 64, 64, 64, 0, false, false>
      <<<g256, 256, 0, stream>>>(Bf, wT + WOFF[3], bs[3], A, 256, 256);
  // pool2: A -> Bf [128,128,64]
  {
    int total8 = BATCH * 128 * 128 * 64 / 8;
    maxpool2_nhwc<<<(total8 + 255) / 256, 256, 0, stream>>>(A, Bf, 64, 256, 256, total8);
  }
  // up1: Bf -> A [256,256,64]
  {
    int total8 = BATCH * 256 * 256 * 64 / 8;
    upsample2_nhwc<<<(total8 + 255) / 256, 256, 0, stream>>>(Bf, A, 64, 128, 128, total8);
  }
  // conv4: A -> Bf [256,256,64]
  conv_mfma<64, 64, 64, 64, 0, false, false>
      <<<g256, 256, 0, stream>>>(A, wT + WOFF[4], bs[4], Bf, 256, 256);
  // conv5: Bf -> A [256,256,32]
  conv_mfma<64, 32, 64, 32, 0, false, false>
      <<<g256, 256, 0, stream>>>(Bf, wT + WOFF[5], bs[5], A, 256, 256);
  // up2: A -> Bf [512,512,32]
  {
    int total8 = BATCH * 512 * 512 * 32 / 8;
    upsample2_nhwc<<<(total8 + 255) / 256, 256, 0, stream>>>(A, Bf, 32, 256, 256, total8);
  }
  // conv6: Bf -> A [512,512,32]
  conv_mfma<32, 32, 32, 32, 0, false, false>
      <<<g512, 256, 0, stream>>>(Bf, wT + WOFF[6], bs[6], A, 512, 512);
  // conv7 + tanh: A -> flow (NCHW f32, 2ch)
  conv_mfma<32, 16, 32, 2, 1, false, true>
      <<<g512, 256, 0, stream>>>(A, wT + WOFF[7], bs[7], flow, 512, 512);
  // deformed
  {
    int total = BATCH * HH * WW;
    deformed_k<<<(total + 255) / 256, 256, 0, stream>>>(flow, temp, def);
  }
  // patches (also overwrites the wT stash)
  {
    int total = BATCH * 256 * 64 * 64;
    patches_k<<<(total + 255) / 256, 256, 0, stream>>>(x, def, out);
  }
}

// Round 3
// 423.990 us; speedup vs baseline: 9.7455x; 1.0203x over previous
//
#include <hip/hip_runtime.h>
#include <hip/hip_bf16.h>

typedef __hip_bfloat16 bf16;
typedef unsigned short ushort_t;
typedef __attribute__((ext_vector_type(8))) short short8;
typedef __attribute__((ext_vector_type(4))) float float4v;

#define BATCH 4
#define HH 512
#define WW 512

__device__ __forceinline__ ushort_t f2bfu(float f) {
  __hip_bfloat16 h = __float2bfloat16(f);
  union { __hip_bfloat16 h; ushort_t u; } c;
  c.h = h;
  return c.u;
}
__device__ __forceinline__ float bfu2f(ushort_t u) {
  return __uint_as_float(((unsigned)u) << 16);
}

// async global->LDS DMA, 16 B per lane; LDS dest = wave-uniform base + lane*16
__device__ __forceinline__ void dma16(void* lds, const void* g) {
  __builtin_amdgcn_global_load_lds(
      (const __attribute__((address_space(1))) unsigned int*)g,
      (__attribute__((address_space(3))) unsigned int*)lds, 16, 0, 0);
}

// ---------------------------------------------------------------------------
// Weight prep: w[l] OIHW f32  ->  wT[l] = [tap(9)][COUT_PAD][CIN_PAD] bf16
// ---------------------------------------------------------------------------
struct WP { const float* w[8]; };

__global__ __launch_bounds__(256) void prep_w(WP wp, bf16* __restrict__ dst) {
  const int O[8]   = {32, 32, 64, 64, 64, 32, 32, 2};
  const int I[8]   = {3, 32, 32, 64, 64, 64, 32, 32};
  const int OP[8]  = {32, 32, 64, 64, 64, 32, 32, 16};
  const int IP[8]  = {32, 32, 32, 64, 64, 64, 32, 32};
  const int OFF[8] = {0, 9216, 18432, 36864, 73728, 110592, 129024, 138240};
  int l = blockIdx.y;
  int e = blockIdx.x * 256 + threadIdx.x;
  int n = 9 * OP[l] * IP[l];
  if (e >= n) return;
  int tap = e / (OP[l] * IP[l]);
  int rem = e - tap * OP[l] * IP[l];
  int o = rem / IP[l];
  int i = rem - o * IP[l];
  float v = 0.0f;
  if (o < O[l] && i < I[l]) v = wp.w[l][((o * I[l]) + i) * 9 + tap];
  dst[OFF[l] + e] = __float2bfloat16(v);
}

// ---------------------------------------------------------------------------
// Implicit-GEMM 3x3 conv (pad 1) via mfma_f32_16x16x32_bf16, NHWC bf16 acts.
// Block: 256 thr (4 waves), 16x16 pixel tile; wave w covers rows 4w..4w+3.
// Interior blocks: halo rows staged by global_load_lds dwordx4 (1 KiB/row),
// x-halo columns by ds_write. Border blocks: checked VALU path.
// IN_MODE: 0=NHWC bf16, 1=NCHW f32 (conv0).
// OUT_MODE: 0=NHWC bf16, 1=NCHW f32, 2=NCHW f32 + fused deformed epilogue.
// ---------------------------------------------------------------------------
template <int CIN, int COUT, int CINR, int COUTR, int ACT, int IN_MODE,
          int OUT_MODE>
__global__ __launch_bounds__(256) void conv_mfma(
    const void* __restrict__ in_, const bf16* __restrict__ wt,
    const float* __restrict__ bias, void* __restrict__ out_, int H, int W,
    const float* __restrict__ temp, float* __restrict__ def) {
  constexpr int MT = COUT / 16;
  constexpr int CK = 32;
  __shared__ alignas(16) bf16 in_lds[324 * CK];  // 18x18 halo x 32ch
  __shared__ alignas(16) bf16 w_lds[9 * COUT * CK];

  const int tid = threadIdx.x;
  const int lane = tid & 63;
  const int wid = tid >> 6;
  const int lm = lane & 15;
  const int quad = lane >> 4;
  const int x0 = blockIdx.x * 16;
  const int y0 = blockIdx.y * 16;
  const int b = blockIdx.z;
  const bool interior =
      (x0 >= 1) && (x0 + 16 <= W - 1) && (y0 >= 1) && (y0 + 16 <= H - 1);

  float4v acc[MT][4];
#pragma unroll
  for (int mt = 0; mt < MT; ++mt) {
    float4v bv;
    if constexpr (COUTR == COUT) {
      bv = *(const float4v*)(bias + mt * 16 + quad * 4);
    } else {
#pragma unroll
      for (int r = 0; r < 4; ++r) {
        int co = mt * 16 + quad * 4 + r;
        bv[r] = (co < COUTR) ? bias[co] : 0.0f;
      }
    }
#pragma unroll
    for (int nt = 0; nt < 4; ++nt) acc[mt][nt] = bv;
  }

  for (int c0 = 0; c0 < CIN; c0 += CK) {
    // ---- stage input halo tile into LDS ----
    if constexpr (IN_MODE == 1) {
      // conv0: x is NCHW f32 with CINR(=3) real channels; pad to CK zeros.
      const float* in = (const float*)in_;
      const uint4 z = {0, 0, 0, 0};
      for (int pix = tid; pix < 324; pix += 256) {
        int hy = pix / 18, hx = pix - hy * 18;
        int gy = y0 - 1 + hy, gx = x0 - 1 + hx;
        union { uint4 v; ushort_t u[8]; } pk;
        pk.v = z;
        if (gy >= 0 && gy < H && gx >= 0 && gx < W) {
          long base = (((long)b * CINR) * H + gy) * (long)W + gx;
#pragma unroll
          for (int c = 0; c < CINR; ++c)
            pk.u[c] = f2bfu(in[base + (long)c * H * W]);
        }
        uint4* dst = (uint4*)&in_lds[pix * CK];
        dst[0] = pk.v;
        dst[1] = z;
        dst[2] = z;
        dst[3] = z;
      }
    } else if (interior) {
      const bf16* in = (const bf16*)in_;
      // core: one DMA per halo row (16 px x 64 B = 1 KiB = 64 lanes x 16 B)
      for (int r = wid; r < 18; r += 4) {
        int gy = y0 - 1 + r;
        const bf16* gsrc = in + (((long)b * H + gy) * W + x0) * CIN + c0 +
                           (lane >> 2) * CIN + (lane & 3) * 8;
        dma16(&in_lds[(r * 18 + 1) * CK], gsrc);
      }
      // x-halo: 2 columns x 18 rows x 4 segs = 144 b128 units
      if (tid < 144) {
        int r = tid >> 3;
        int side = (tid >> 2) & 1;
        int seg = tid & 3;
        int gx = side ? (x0 + 16) : (x0 - 1);
        int gy = y0 - 1 + r;
        uint4 v = *(const uint4*)(in + (((long)b * H + gy) * W + gx) * CIN +
                                  c0 + seg * 8);
        *(uint4*)&in_lds[(r * 18 + (side ? 17 : 0)) * CK + seg * 8] = v;
      }
    } else {
      const bf16* in = (const bf16*)in_;
      for (int u = tid; u < 324 * 4; u += 256) {
        int pix = u >> 2;
        int seg = u & 3;
        int hy = pix / 18, hx = pix - hy * 18;
        int gy = y0 - 1 + hy, gx = x0 - 1 + hx;
        uint4 v = {0, 0, 0, 0};
        if (gy >= 0 && gy < H && gx >= 0 && gx < W)
          v = *(const uint4*)(in + (((long)b * H + gy) * W + gx) * CIN + c0 +
                              seg * 8);
        *(uint4*)&in_lds[pix * CK + seg * 8] = v;
      }
    }
    // ---- stage weight chunk [9][COUT][CK] ----
    {
      constexpr int WUNITS = 9 * COUT * CK / 8;
      for (int u = tid; u < WUNITS; u += 256) {
        int to = u >> 2;
        int seg = u & 3;
        uint4 v = *(const uint4*)(wt + (long)to * CIN + c0 + seg * 8);
        *(uint4*)&w_lds[to * CK + seg * 8] = v;
      }
    }
    __syncthreads();

    // ---- 9 taps x K=32 MFMA ----
#pragma unroll
    for (int tap = 0; tap < 9; ++tap) {
      const int r = tap / 3, s = tap - r * 3;
      short8 afrag[MT], bfrag[4];
#pragma unroll
      for (int mt = 0; mt < MT; ++mt)
        afrag[mt] =
            *(const short8*)&w_lds[(tap * COUT + mt * 16 + lm) * CK + quad * 8];
#pragma unroll
      for (int nt = 0; nt < 4; ++nt) {
        int py = 4 * wid + nt;
        bfrag[nt] =
            *(const short8*)&in_lds[((py + r) * 18 + lm + s) * CK + quad * 8];
      }
#pragma unroll
      for (int mt = 0; mt < MT; ++mt)
#pragma unroll
        for (int nt = 0; nt < 4; ++nt)
          acc[mt][nt] = __builtin_amdgcn_mfma_f32_16x16x32_bf16(
              afrag[mt], bfrag[nt], acc[mt][nt], 0, 0, 0);
    }
    __syncthreads();
  }

  // ---- epilogue ----
#pragma unroll
  for (int mt = 0; mt < MT; ++mt) {
#pragma unroll
    for (int nt = 0; nt < 4; ++nt) {
      int gy = y0 + 4 * wid + nt;
      int gx = x0 + lm;
      float4v v = acc[mt][nt];
      if constexpr (OUT_MODE == 0) {
        bf16* out = (bf16*)out_;
        union { uint2 v; ushort_t u[4]; } pk;
#pragma unroll
        for (int r = 0; r < 4; ++r) {
          float f = v[r];
          if (ACT == 0) f = fmaxf(f, 0.0f);
          pk.u[r] = f2bfu(f);
        }
        *(uint2*)&out[(((long)b * H + gy) * W + gx) * COUT + mt * 16 +
                      quad * 4] = pk.v;
      } else if constexpr (OUT_MODE == 1) {
        float* out = (float*)out_;
#pragma unroll
        for (int r = 0; r < 4; ++r) {
          int co = mt * 16 + quad * 4 + r;
          if (co < COUTR) {
            float f = v[r];
            if (ACT == 0)
              f = fmaxf(f, 0.0f);
            else
              f = tanhf(f);
            out[(((long)b * COUTR + co) * H + gy) * (long)W + gx] = f;
          }
        }
      } else {
        // OUT_MODE 2: flow (NCHW f32, 2ch) + fused deformed [B,H,W,2].
        // COUTR=2 -> both channels live in quad 0's regs r=0,1.
        float* out = (float*)out_;
        if (quad == 0) {
          float fx = tanhf(v[0]);
          float fy = tanhf(v[1]);
          out[(((long)b * 2 + 0) * H + gy) * (long)W + gx] = fx;
          out[(((long)b * 2 + 1) * H + gy) * (long)W + gx] = fy;
          float T = temp[0];
          float2 d;
          d.x = -1.0f + gx * (2.0f / 511.0f) + fx * T;
          d.y = -1.0f + gy * (2.0f / 511.0f) + fy * T;
          *(float2*)&def[(((long)b * H + gy) * W + gx) * 2] = d;
        }
      }
    }
  }
}

// ---------------------------------------------------------------------------
// MaxPool2d(2) NHWC, 8 channels per thread (uint4).
// ---------------------------------------------------------------------------
__global__ __launch_bounds__(256) void maxpool2_nhwc(const bf16* __restrict__ in,
                                                     bf16* __restrict__ out,
                                                     int C, int H, int W,
                                                     int total8) {
  int i = blockIdx.x * 256 + threadIdx.x;
  if (i >= total8) return;
  int C8 = C >> 3;
  int c8 = i % C8;
  int t = i / C8;
  int Wo = W >> 1, Ho = H >> 1;
  int x = t % Wo;
  t /= Wo;
  int y = t % Ho;
  int bb = t / Ho;
  const bf16* p = in + ((((long)bb * H + 2 * y) * W + 2 * x) * C) + c8 * 8;
  union U { uint4 v; ushort_t u[8]; } a, b2, c2, d, o;
  a.v = *(const uint4*)p;
  b2.v = *(const uint4*)(p + C);
  c2.v = *(const uint4*)(p + (long)W * C);
  d.v = *(const uint4*)(p + (long)W * C + C);
#pragma unroll
  for (int j = 0; j < 8; ++j) {
    float fm = bfu2f(a.u[j]);
    ushort_t m = a.u[j];
    float f = bfu2f(b2.u[j]);
    if (f > fm) { fm = f; m = b2.u[j]; }
    f = bfu2f(c2.u[j]);
    if (f > fm) { fm = f; m = c2.u[j]; }
    f = bfu2f(d.u[j]);
    if (f > fm) { fm = f; m = d.u[j]; }
    o.u[j] = m;
  }
  *(uint4*)(out + ((((long)bb * Ho + y) * Wo + x) * C) + c8 * 8) = o.v;
}

// ---------------------------------------------------------------------------
// Bilinear upsample x2 (half-pixel, edge clamp) NHWC, 8 ch per thread.
// ---------------------------------------------------------------------------
__global__ __launch_bounds__(256) void upsample2_nhwc(const bf16* __restrict__ in,
                                                      bf16* __restrict__ out,
                                                      int C, int H, int W,
                                                      int total8) {
  int i = blockIdx.x * 256 + threadIdx.x;
  if (i >= total8) return;
  int C8 = C >> 3;
  int c8 = i % C8;
  int t = i / C8;
  int Wo = 2 * W, Ho = 2 * H;
  int x = t % Wo;
  t /= Wo;
  int y = t % Ho;
  int bb = t / Ho;
  float sy = y * 0.5f - 0.25f;
  float sx = x * 0.5f - 0.25f;
  int y0 = (int)floorf(sy);
  int x0 = (int)floorf(sx);
  float wy = sy - (float)y0;
  float wx = sx - (float)x0;
  int y0c = max(y0, 0), y1c = min(y0 + 1, H - 1);
  int x0c = max(x0, 0), x1c = min(x0 + 1, W - 1);
  const bf16* p = in + ((long)bb * H * W) * C + c8 * 8;
  union U { uint4 v; ushort_t u[8]; } v00, v01, v10, v11, o;
  v00.v = *(const uint4*)(p + ((long)y0c * W + x0c) * C);
  v01.v = *(const uint4*)(p + ((long)y0c * W + x1c) * C);
  v10.v = *(const uint4*)(p + ((long)y1c * W + x0c) * C);
  v11.v = *(const uint4*)(p + ((long)y1c * W + x1c) * C);
#pragma unroll
  for (int j = 0; j < 8; ++j) {
    float f = (1.0f - wy) * ((1.0f - wx) * bfu2f(v00.u[j]) + wx * bfu2f(v01.u[j])) +
              wy * ((1.0f - wx) * bfu2f(v10.u[j]) + wx * bfu2f(v11.u[j]));
    o.u[j] = f2bfu(f);
  }
  *(uint4*)(out + ((((long)bb * Ho + y) * Wo + x) * C) + c8 * 8) = o.v;
}

// ---------------------------------------------------------------------------
// patches: grid_sample bilinear, zeros padding -> out [B,256,3,64,64]
// ---------------------------------------------------------------------------
__global__ __launch_bounds__(256) void patches_k(const float* __restrict__ x,
                                                 const float* __restrict__ def,
                                                 float* __restrict__ out) {
  int i = blockIdx.x * 256 + threadIdx.x;
  int pj = i & 63;
  int t = i >> 6;
  int pi = t & 63;
  t >>= 6;
  int n = t & 255;
  int b = t >> 8;
  if (b >= BATCH) return;
  int hi = n >> 4, wi = n & 15;
  const float* dptr = def + (((long)b * HH + hi * 32) * WW + wi * 32) * 2;
  float cx = dptr[0], cy = dptr[1];
  float pgx = cx + (-1.0f + pj * (2.0f / 63.0f)) * 0.125f;
  float pgy = cy + (-1.0f + pi * (2.0f / 63.0f)) * 0.125f;
  float ix = ((pgx + 1.0f) * 512.0f - 1.0f) * 0.5f;
  float iy = ((pgy + 1.0f) * 512.0f - 1.0f) * 0.5f;
  float fx0 = floorf(ix), fy0 = floorf(iy);
  float wx1 = ix - fx0, wy1 = iy - fy0;
  int x0 = (int)fx0, y0 = (int)fy0;
  int x1 = x0 + 1, y1 = y0 + 1;
  bool vx0 = (x0 >= 0) && (x0 <= 511), vx1 = (x1 >= 0) && (x1 <= 511);
  bool vy0 = (y0 >= 0) && (y0 <= 511), vy1 = (y1 >= 0) && (y1 <= 511);
  int cx0 = min(max(x0, 0), 511), cx1 = min(max(x1, 0), 511);
  int cy0 = min(max(y0, 0), 511), cy1 = min(max(y1, 0), 511);
  float w00 = (1.0f - wx1) * (1.0f - wy1) * ((vx0 && vy0) ? 1.0f : 0.0f);
  float w01 = wx1 * (1.0f - wy1) * ((vx1 && vy0) ? 1.0f : 0.0f);
  float w10 = (1.0f - wx1) * wy1 * ((vx0 && vy1) ? 1.0f : 0.0f);
  float w11 = wx1 * wy1 * ((vx1 && vy1) ? 1.0f : 0.0f);
#pragma unroll
  for (int c = 0; c < 3; ++c) {
    const float* img = x + ((long)b * 3 + c) * (HH * WW);
    float v = img[cy0 * WW + cx0] * w00 + img[cy0 * WW + cx1] * w01 +
              img[cy1 * WW + cx0] * w10 + img[cy1 * WW + cx1] * w11;
    out[(((long)b * 256 + n) * 3 + c) * 4096 + pi * 64 + pj] = v;
  }
}

// ---------------------------------------------------------------------------

extern "C" void kernel_launch(void* const* d_in, const int* in_sizes, int n_in,
                              void* d_out, int out_size, void* d_ws,
                              size_t ws_size, hipStream_t stream) {
  const float* x = (const float*)d_in[0];
  WP wp;
  const float* bs[8];
  for (int i = 0; i < 8; ++i) {
    wp.w[i] = (const float*)d_in[1 + 2 * i];
    bs[i] = (const float*)d_in[2 + 2 * i];
  }
  const float* temp = (const float*)d_in[17];

  float* out = (float*)d_out;
  float* flow = out + 12582912;  // [B,2,512,512] f32
  float* def = out + 14680064;   // [B,512,512,2] f32

  // Transposed bf16 weights at the head of the patches region of d_out;
  // patches_k overwrites it LAST.
  bf16* wT = (bf16*)d_out;
  const int WOFF[8] = {0, 9216, 18432, 36864, 73728, 110592, 129024, 138240};

  const size_t bufElems = (size_t)BATCH * 512 * 512 * 32;
  bf16* A = (bf16*)d_ws;
  bf16* Bf = A + bufElems;

  prep_w<<<dim3(144, 8), 256, 0, stream>>>(wp, wT);

  dim3 g512(32, 32, BATCH);
  dim3 g256(16, 16, BATCH);

  // conv0: x (NCHW f32, 3ch) -> A NHWC [512,512,32]
  conv_mfma<32, 32, 3, 32, 0, 1, 0>
      <<<g512, 256, 0, stream>>>(x, wT + WOFF[0], bs[0], A, 512, 512, nullptr, nullptr);
  // conv1: A -> Bf NHWC [512,512,32]
  conv_mfma<32, 32, 32, 32, 0, 0, 0>
      <<<g512, 256, 0, stream>>>(A, wT + WOFF[1], bs[1], Bf, 512, 512, nullptr, nullptr);
  // pool1: Bf -> A [256,256,32]
  {
    int total8 = BATCH * 256 * 256 * 32 / 8;
    maxpool2_nhwc<<<(total8 + 255) / 256, 256, 0, stream>>>(Bf, A, 32, 512, 512, total8);
  }
  // conv2: A -> Bf [256,256,64]
  conv_mfma<32, 64, 32, 64, 0, 0, 0>
      <<<g256, 256, 0, stream>>>(A, wT + WOFF[2], bs[2], Bf, 256, 256, nullptr, nullptr);
  // conv3: Bf -> A [256,256,64]
  conv_mfma<64, 64, 64, 64, 0, 0, 0>
      <<<g256, 256, 0, stream>>>(Bf, wT + WOFF[3], bs[3], A, 256, 256, nullptr, nullptr);
  // pool2: A -> Bf [128,128,64]
  {
    int total8 = BATCH * 128 * 128 * 64 / 8;
    maxpool2_nhwc<<<(total8 + 255) / 256, 256, 0, stream>>>(A, Bf, 64, 256, 256, total8);
  }
  // up1: Bf -> A [256,256,64]
  {
    int total8 = BATCH * 256 * 256 * 64 / 8;
    upsample2_nhwc<<<(total8 + 255) / 256, 256, 0, stream>>>(Bf, A, 64, 128, 128, total8);
  }
  // conv4: A -> Bf [256,256,64]
  conv_mfma<64, 64, 64, 64, 0, 0, 0>
      <<<g256, 256, 0, stream>>>(A, wT + WOFF[4], bs[4], Bf, 256, 256, nullptr, nullptr);
  // conv5: Bf -> A [256,256,32]
  conv_mfma<64, 32, 64, 32, 0, 0, 0>
      <<<g256, 256, 0, stream>>>(Bf, wT + WOFF[5], bs[5], A, 256, 256, nullptr, nullptr);
  // up2: A -> Bf [512,512,32]
  {
    int total8 = BATCH * 512 * 512 * 32 / 8;
    upsample2_nhwc<<<(total8 + 255) / 256, 256, 0, stream>>>(A, Bf, 32, 256, 256, total8);
  }
  // conv6: Bf -> A [512,512,32]
  conv_mfma<32, 32, 32, 32, 0, 0, 0>
      <<<g512, 256, 0, stream>>>(Bf, wT + WOFF[6], bs[6], A, 512, 512, nullptr, nullptr);
  // conv7 + tanh + fused deformed: A -> flow (NCHW f32, 2ch) + def [B,H,W,2]
  conv_mfma<32, 16, 32, 2, 1, 0, 2>
      <<<g512, 256, 0, stream>>>(A, wT + WOFF[7], bs[7], flow, 512, 512, temp, def);
  // patches (overwrites the wT stash)
  {
    int total = BATCH * 256 * 64 * 64;
    patches_k<<<(total + 255) / 256, 256, 0, stream>>>(x, def, out);
  }
}

// Round 4
// 355.494 us; speedup vs baseline: 11.6232x; 1.1927x over previous
//
#include <hip/hip_runtime.h>
#include <hip/hip_bf16.h>

typedef __hip_bfloat16 bf16;
typedef unsigned short ushort_t;
typedef __attribute__((ext_vector_type(8))) short short8;
typedef __attribute__((ext_vector_type(4))) float float4v;

#define BATCH 4
#define HH 512
#define WW 512

__device__ __forceinline__ ushort_t f2bfu(float f) {
  __hip_bfloat16 h = __float2bfloat16(f);
  union { __hip_bfloat16 h; ushort_t u; } c;
  c.h = h;
  return c.u;
}
__device__ __forceinline__ float bfu2f(ushort_t u) {
  return __uint_as_float(((unsigned)u) << 16);
}

// async global->LDS DMA, 16 B per lane; LDS dest = wave-uniform base + lane*16
__device__ __forceinline__ void dma16(void* lds, const void* g) {
  __builtin_amdgcn_global_load_lds(
      (const __attribute__((address_space(1))) unsigned int*)g,
      (__attribute__((address_space(3))) unsigned int*)lds, 16, 0, 0);
}

// ---------------------------------------------------------------------------
// Weight prep: w[l] OIHW f32  ->  wT[l] = [tap(9)][COUT_PAD][CIN_PAD] bf16
// ---------------------------------------------------------------------------
struct WP { const float* w[8]; };

__global__ __launch_bounds__(256) void prep_w(WP wp, bf16* __restrict__ dst) {
  const int O[8]   = {32, 32, 64, 64, 64, 32, 32, 2};
  const int I[8]   = {3, 32, 32, 64, 64, 64, 32, 32};
  const int OP[8]  = {32, 32, 64, 64, 64, 32, 32, 16};
  const int IP[8]  = {32, 32, 32, 64, 64, 64, 32, 32};
  const int OFF[8] = {0, 9216, 18432, 36864, 73728, 110592, 129024, 138240};
  int l = blockIdx.y;
  int e = blockIdx.x * 256 + threadIdx.x;
  int n = 9 * OP[l] * IP[l];
  if (e >= n) return;
  int tap = e / (OP[l] * IP[l]);
  int rem = e - tap * OP[l] * IP[l];
  int o = rem / IP[l];
  int i = rem - o * IP[l];
  float v = 0.0f;
  if (o < O[l] && i < I[l]) v = wp.w[l][((o * I[l]) + i) * 9 + tap];
  dst[OFF[l] + e] = __float2bfloat16(v);
}

// ---------------------------------------------------------------------------
// pack_x: NCHW f32 (3ch) -> NHWC-8 bf16 (ch 3..7 zero)
// ---------------------------------------------------------------------------
__global__ __launch_bounds__(256) void pack_x(const float* __restrict__ x,
                                              bf16* __restrict__ xp) {
  int i = blockIdx.x * 256 + threadIdx.x;  // over B*H*W
  if (i >= BATCH * HH * WW) return;
  int b = i / (HH * WW);
  int px = i - b * (HH * WW);
  union { uint4 v; ushort_t s[8]; } o;
  o.v = make_uint4(0, 0, 0, 0);
  const float* p = x + (long)b * 3 * HH * WW + px;
  o.s[0] = f2bfu(p[0]);
  o.s[1] = f2bfu(p[HH * WW]);
  o.s[2] = f2bfu(p[2 * HH * WW]);
  *(uint4*)&xp[(long)i * 8] = o.v;
}

// ---------------------------------------------------------------------------
// Implicit-GEMM 3x3 conv (pad 1) via mfma_f32_16x16x32_bf16, NHWC bf16 acts.
// Block: 256 thr (4 waves), 16x16 OUTPUT pixel tile; wave w rows 4w..4w+3.
// IN_MODE:  0 = NHWC bf16 same-res (DMA fast path for interior blocks)
//           2 = NHWC bf16 HALF-res source, fused x2 bilinear upsample staging
//           3 = NHWC-8 packed bf16 (conv0; ch 8..31 zero)
// OUT_MODE: 0 = NHWC bf16 (+relu)
//           2 = flow NCHW f32 (tanh) + fused deformed [B,H,W,2]
//           3 = NHWC bf16, fused relu + 2x2 maxpool (writes H/2 x W/2)
// ---------------------------------------------------------------------------
template <int CIN, int COUT, int COUTR, int ACT, int IN_MODE, int OUT_MODE>
__global__ __launch_bounds__(256) void conv_mfma(
    const void* __restrict__ in_, const bf16* __restrict__ wt,
    const float* __restrict__ bias, void* __restrict__ out_, int H, int W,
    const float* __restrict__ temp, float* __restrict__ def) {
  constexpr int MT = COUT / 16;
  constexpr int CK = 32;
  __shared__ alignas(16) bf16 in_lds[324 * CK];  // 18x18 halo x 32ch
  __shared__ alignas(16) bf16 w_lds[9 * COUT * CK];

  const int tid = threadIdx.x;
  const int lane = tid & 63;
  const int wid = tid >> 6;
  const int lm = lane & 15;
  const int quad = lane >> 4;
  const int x0 = blockIdx.x * 16;
  const int y0 = blockIdx.y * 16;
  const int b = blockIdx.z;

  float4v acc[MT][4];
#pragma unroll
  for (int mt = 0; mt < MT; ++mt) {
    float4v bv;
    if constexpr (COUTR == COUT) {
      bv = *(const float4v*)(bias + mt * 16 + quad * 4);
    } else {
#pragma unroll
      for (int r = 0; r < 4; ++r) {
        int co = mt * 16 + quad * 4 + r;
        bv[r] = (co < COUTR) ? bias[co] : 0.0f;
      }
    }
#pragma unroll
    for (int nt = 0; nt < 4; ++nt) acc[mt][nt] = bv;
  }

  for (int c0 = 0; c0 < CIN; c0 += CK) {
    // ---- stage input halo tile into LDS ----
    if constexpr (IN_MODE == 3) {
      // packed NHWC-8 source; segs 1..3 zero
      const bf16* in = (const bf16*)in_;
      for (int u = tid; u < 324 * 4; u += 256) {
        int px = u >> 2;
        int seg = u & 3;
        int hy = px / 18, hx = px - hy * 18;
        int gy = y0 - 1 + hy, gx = x0 - 1 + hx;
        uint4 v = make_uint4(0, 0, 0, 0);
        if (seg == 0 && gy >= 0 && gy < H && gx >= 0 && gx < W)
          v = *(const uint4*)(in + (((long)b * H + gy) * W + gx) * 8);
        *(uint4*)&in_lds[px * CK + seg * 8] = v;
      }
    } else if constexpr (IN_MODE == 2) {
      // fused x2 bilinear upsample from half-res NHWC source (edge clamp),
      // zero outside full-res image (conv pad)
      const bf16* in = (const bf16*)in_;
      const int Hs = H >> 1, Ws = W >> 1;
      for (int u = tid; u < 324 * 4; u += 256) {
        int px = u >> 2;
        int seg = u & 3;
        int hy = px / 18, hx = px - hy * 18;
        int gy = y0 - 1 + hy, gx = x0 - 1 + hx;
        uint4 o = make_uint4(0, 0, 0, 0);
        if (gy >= 0 && gy < H && gx >= 0 && gx < W) {
          int ys = (gy >> 1) - ((gy & 1) ? 0 : 1);
          int xs = (gx >> 1) - ((gx & 1) ? 0 : 1);
          float wy = (gy & 1) ? 0.25f : 0.75f;
          float wx = (gx & 1) ? 0.25f : 0.75f;
          int y0c = max(ys, 0), y1c = min(ys + 1, Hs - 1);
          int x0c = max(xs, 0), x1c = min(xs + 1, Ws - 1);
          const bf16* p = in + ((long)b * Hs * Ws) * CIN + c0 + seg * 8;
          union { uint4 v; ushort_t s[8]; } a00, a01, a10, a11, r;
          a00.v = *(const uint4*)(p + ((long)y0c * Ws + x0c) * CIN);
          a01.v = *(const uint4*)(p + ((long)y0c * Ws + x1c) * CIN);
          a10.v = *(const uint4*)(p + ((long)y1c * Ws + x0c) * CIN);
          a11.v = *(const uint4*)(p + ((long)y1c * Ws + x1c) * CIN);
#pragma unroll
          for (int j = 0; j < 8; ++j) {
            float f = (1.0f - wy) * ((1.0f - wx) * bfu2f(a00.s[j]) +
                                     wx * bfu2f(a01.s[j])) +
                      wy * ((1.0f - wx) * bfu2f(a10.s[j]) +
                            wx * bfu2f(a11.s[j]));
            r.s[j] = f2bfu(f);
          }
          o = r.v;
        }
        *(uint4*)&in_lds[px * CK + seg * 8] = o;
      }
    } else {
      const bool interior =
          (x0 >= 1) && (x0 + 16 <= W - 1) && (y0 >= 1) && (y0 + 16 <= H - 1);
      const bf16* in = (const bf16*)in_;
      if (interior) {
        // core: one DMA per halo row (16 px x 64 B = 1 KiB = 64 lanes x 16 B)
        for (int r = wid; r < 18; r += 4) {
          int gy = y0 - 1 + r;
          const bf16* gsrc = in + (((long)b * H + gy) * W + x0) * CIN + c0 +
                             (lane >> 2) * CIN + (lane & 3) * 8;
          dma16(&in_lds[(r * 18 + 1) * CK], gsrc);
        }
        // x-halo: 2 columns x 18 rows x 4 segs = 144 b128 units
        if (tid < 144) {
          int r = tid >> 3;
          int side = (tid >> 2) & 1;
          int seg = tid & 3;
          int gx = side ? (x0 + 16) : (x0 - 1);
          int gy = y0 - 1 + r;
          uint4 v = *(const uint4*)(in + (((long)b * H + gy) * W + gx) * CIN +
                                    c0 + seg * 8);
          *(uint4*)&in_lds[(r * 18 + (side ? 17 : 0)) * CK + seg * 8] = v;
        }
      } else {
        for (int u = tid; u < 324 * 4; u += 256) {
          int px = u >> 2;
          int seg = u & 3;
          int hy = px / 18, hx = px - hy * 18;
          int gy = y0 - 1 + hy, gx = x0 - 1 + hx;
          uint4 v = make_uint4(0, 0, 0, 0);
          if (gy >= 0 && gy < H && gx >= 0 && gx < W)
            v = *(const uint4*)(in + (((long)b * H + gy) * W + gx) * CIN + c0 +
                                seg * 8);
          *(uint4*)&in_lds[px * CK + seg * 8] = v;
        }
      }
    }
    // ---- stage weight chunk [9][COUT][CK] ----
    {
      constexpr int WUNITS = 9 * COUT * CK / 8;
      for (int u = tid; u < WUNITS; u += 256) {
        int to = u >> 2;
        int seg = u & 3;
        uint4 v = *(const uint4*)(wt + (long)to * CIN + c0 + seg * 8);
        *(uint4*)&w_lds[to * CK + seg * 8] = v;
      }
    }
    __syncthreads();

    // ---- 9 taps x K=32 MFMA ----
#pragma unroll
    for (int tap = 0; tap < 9; ++tap) {
      const int r = tap / 3, s = tap - r * 3;
      short8 afrag[MT], bfrag[4];
#pragma unroll
      for (int mt = 0; mt < MT; ++mt)
        afrag[mt] =
            *(const short8*)&w_lds[(tap * COUT + mt * 16 + lm) * CK + quad * 8];
#pragma unroll
      for (int nt = 0; nt < 4; ++nt) {
        int py = 4 * wid + nt;
        bfrag[nt] =
            *(const short8*)&in_lds[((py + r) * 18 + lm + s) * CK + quad * 8];
      }
#pragma unroll
      for (int mt = 0; mt < MT; ++mt)
#pragma unroll
        for (int nt = 0; nt < 4; ++nt)
          acc[mt][nt] = __builtin_amdgcn_mfma_f32_16x16x32_bf16(
              afrag[mt], bfrag[nt], acc[mt][nt], 0, 0, 0);
    }
    __syncthreads();
  }

  // ---- epilogue ----
  if constexpr (OUT_MODE == 3) {
    // fused relu + 2x2 maxpool -> NHWC bf16 at H/2 x W/2
    bf16* out = (bf16*)out_;
    const int Ho = H >> 1, Wo = W >> 1;
#pragma unroll
    for (int mt = 0; mt < MT; ++mt) {
#pragma unroll
      for (int g = 0; g < 2; ++g) {
        float4v m;
#pragma unroll
        for (int r = 0; r < 4; ++r)
          m[r] = fmaxf(fmaxf(acc[mt][2 * g][r], acc[mt][2 * g + 1][r]), 0.0f);
#pragma unroll
        for (int r = 0; r < 4; ++r) m[r] = fmaxf(m[r], __shfl_xor(m[r], 1, 64));
        if ((lm & 1) == 0) {
          int pyo = (y0 >> 1) + 2 * wid + g;
          int pxo = (x0 >> 1) + (lm >> 1);
          union { uint2 v; ushort_t s[4]; } pk;
#pragma unroll
          for (int r = 0; r < 4; ++r) pk.s[r] = f2bfu(m[r]);
          *(uint2*)&out[(((long)b * Ho + pyo) * Wo + pxo) * COUT + mt * 16 +
                        quad * 4] = pk.v;
        }
      }
    }
  } else {
#pragma unroll
    for (int mt = 0; mt < MT; ++mt) {
#pragma unroll
      for (int nt = 0; nt < 4; ++nt) {
        int gy = y0 + 4 * wid + nt;
        int gx = x0 + lm;
        float4v v = acc[mt][nt];
        if constexpr (OUT_MODE == 0) {
          bf16* out = (bf16*)out_;
          union { uint2 v; ushort_t s[4]; } pk;
#pragma unroll
          for (int r = 0; r < 4; ++r) pk.s[r] = f2bfu(fmaxf(v[r], 0.0f));
          *(uint2*)&out[(((long)b * H + gy) * W + gx) * COUT + mt * 16 +
                        quad * 4] = pk.v;
        } else {
          // OUT_MODE 2: flow (NCHW f32, 2ch, tanh) + fused deformed [B,H,W,2]
          float* out = (float*)out_;
          if (quad == 0) {
            float fx = tanhf(v[0]);
            float fy = tanhf(v[1]);
            out[(((long)b * 2 + 0) * H + gy) * (long)W + gx] = fx;
            out[(((long)b * 2 + 1) * H + gy) * (long)W + gx] = fy;
            float T = temp[0];
            float2 d;
            d.x = -1.0f + gx * (2.0f / 511.0f) + fx * T;
            d.y = -1.0f + gy * (2.0f / 511.0f) + fy * T;
            *(float2*)&def[(((long)b * H + gy) * W + gx) * 2] = d;
          }
        }
      }
    }
  }
}

// ---------------------------------------------------------------------------
// patches: grid_sample bilinear, zeros padding -> out [B,256,3,64,64]
// ---------------------------------------------------------------------------
__global__ __launch_bounds__(256) void patches_k(const float* __restrict__ x,
                                                 const float* __restrict__ def,
                                                 float* __restrict__ out) {
  int i = blockIdx.x * 256 + threadIdx.x;
  int pj = i & 63;
  int t = i >> 6;
  int pi = t & 63;
  t >>= 6;
  int n = t & 255;
  int b = t >> 8;
  if (b >= BATCH) return;
  int hi = n >> 4, wi = n & 15;
  const float* dptr = def + (((long)b * HH + hi * 32) * WW + wi * 32) * 2;
  float cx = dptr[0], cy = dptr[1];
  float pgx = cx + (-1.0f + pj * (2.0f / 63.0f)) * 0.125f;
  float pgy = cy + (-1.0f + pi * (2.0f / 63.0f)) * 0.125f;
  float ix = ((pgx + 1.0f) * 512.0f - 1.0f) * 0.5f;
  float iy = ((pgy + 1.0f) * 512.0f - 1.0f) * 0.5f;
  float fx0 = floorf(ix), fy0 = floorf(iy);
  float wx1 = ix - fx0, wy1 = iy - fy0;
  int x0 = (int)fx0, y0 = (int)fy0;
  int x1 = x0 + 1, y1 = y0 + 1;
  bool vx0 = (x0 >= 0) && (x0 <= 511), vx1 = (x1 >= 0) && (x1 <= 511);
  bool vy0 = (y0 >= 0) && (y0 <= 511), vy1 = (y1 >= 0) && (y1 <= 511);
  int cx0 = min(max(x0, 0), 511), cx1 = min(max(x1, 0), 511);
  int cy0 = min(max(y0, 0), 511), cy1 = min(max(y1, 0), 511);
  float w00 = (1.0f - wx1) * (1.0f - wy1) * ((vx0 && vy0) ? 1.0f : 0.0f);
  float w01 = wx1 * (1.0f - wy1) * ((vx1 && vy0) ? 1.0f : 0.0f);
  float w10 = (1.0f - wx1) * wy1 * ((vx0 && vy1) ? 1.0f : 0.0f);
  float w11 = wx1 * wy1 * ((vx1 && vy1) ? 1.0f : 0.0f);
#pragma unroll
  for (int c = 0; c < 3; ++c) {
    const float* img = x + ((long)b * 3 + c) * (HH * WW);
    float v = img[cy0 * WW + cx0] * w00 + img[cy0 * WW + cx1] * w01 +
              img[cy1 * WW + cx0] * w10 + img[cy1 * WW + cx1] * w11;
    out[(((long)b * 256 + n) * 3 + c) * 4096 + pi * 64 + pj] = v;
  }
}

// ---------------------------------------------------------------------------

extern "C" void kernel_launch(void* const* d_in, const int* in_sizes, int n_in,
                              void* d_out, int out_size, void* d_ws,
                              size_t ws_size, hipStream_t stream) {
  const float* x = (const float*)d_in[0];
  WP wp;
  const float* bs[8];
  for (int i = 0; i < 8; ++i) {
    wp.w[i] = (const float*)d_in[1 + 2 * i];
    bs[i] = (const float*)d_in[2 + 2 * i];
  }
  const float* temp = (const float*)d_in[17];

  float* out = (float*)d_out;
  float* flow = out + 12582912;  // [B,2,512,512] f32
  float* def = out + 14680064;   // [B,512,512,2] f32

  // Transposed bf16 weights at the head of the patches region of d_out;
  // patches_k overwrites it LAST.
  bf16* wT = (bf16*)d_out;
  const int WOFF[8] = {0, 9216, 18432, 36864, 73728, 110592, 129024, 138240};

  const size_t bufElems = (size_t)BATCH * 512 * 512 * 32;
  bf16* A = (bf16*)d_ws;
  bf16* Bf = A + bufElems;
  bf16* xp = Bf + bufElems;  // packed NHWC-8 input, 16.8 MB

  prep_w<<<dim3(144, 8), 256, 0, stream>>>(wp, wT);
  {
    int total = BATCH * HH * WW;
    pack_x<<<(total + 255) / 256, 256, 0, stream>>>(x, xp);
  }

  dim3 g512(32, 32, BATCH);
  dim3 g256(16, 16, BATCH);
  dim3 g128(8, 8, BATCH);

  // conv0: xp (NHWC-8) -> A [512,512,32]
  conv_mfma<32, 32, 32, 0, 3, 0>
      <<<g512, 256, 0, stream>>>(xp, wT + WOFF[0], bs[0], A, 512, 512, nullptr, nullptr);
  // conv1 + relu + pool: A -> Bf [256,256,32]
  conv_mfma<32, 32, 32, 0, 0, 3>
      <<<g512, 256, 0, stream>>>(A, wT + WOFF[1], bs[1], Bf, 512, 512, nullptr, nullptr);
  // conv2: Bf -> A [256,256,64]
  conv_mfma<32, 64, 64, 0, 0, 0>
      <<<g256, 256, 0, stream>>>(Bf, wT + WOFF[2], bs[2], A, 256, 256, nullptr, nullptr);
  // conv3 + relu + pool: A -> Bf [128,128,64]
  conv_mfma<64, 64, 64, 0, 0, 3>
      <<<g256, 256, 0, stream>>>(A, wT + WOFF[3], bs[3], Bf, 256, 256, nullptr, nullptr);
  // conv4 (fused up1): Bf(128² src) -> A [256,256,64]
  conv_mfma<64, 64, 64, 0, 2, 0>
      <<<g256, 256, 0, stream>>>(Bf, wT + WOFF[4], bs[4], A, 256, 256, nullptr, nullptr);
  // conv5: A -> Bf [256,256,32]
  conv_mfma<64, 32, 32, 0, 0, 0>
      <<<g256, 256, 0, stream>>>(A, wT + WOFF[5], bs[5], Bf, 256, 256, nullptr, nullptr);
  // conv6 (fused up2): Bf(256² src) -> A [512,512,32]
  conv_mfma<32, 32, 32, 0, 2, 0>
      <<<g512, 256, 0, stream>>>(Bf, wT + WOFF[6], bs[6], A, 512, 512, nullptr, nullptr);
  // conv7 + tanh + fused deformed: A -> flow + def
  conv_mfma<32, 16, 2, 1, 0, 2>
      <<<g512, 256, 0, stream>>>(A, wT + WOFF[7], bs[7], flow, 512, 512, temp, def);
  // patches (overwrites the wT stash)
  {
    int total = BATCH * 256 * 64 * 64;
    patches_k<<<(total + 255) / 256, 256, 0, stream>>>(x, def, out);
  }
}